// Round 8
// baseline (544.420 us; speedup 1.0000x reference)
//
#include <hip/hip_runtime.h>
#include <hip/hip_bf16.h>
#include <cstdint>
#include <cstddef>

using bf16 = __hip_bfloat16;
#define DEV __device__ __forceinline__

typedef short s16x8 __attribute__((ext_vector_type(8)));
typedef float f32x4 __attribute__((ext_vector_type(4)));

DEV float b2f(bf16 x){ return __bfloat162float(x); }
DEV bf16  f2b(float x){ return __float2bfloat16(x); }
DEV float u2f(unsigned u){ union{unsigned u; float f;} c; c.u=u; return c.f; }
DEV unsigned f2u(float f){ union{float f; unsigned u;} c; c.f=f; return c.u; }
DEV unsigned short f2bu(float f){ unsigned u = f2u(f); u += 0x7FFFu + ((u>>16)&1u); return (unsigned short)(u>>16); }
DEV float bs2f(unsigned short s){ return u2f(((unsigned)s)<<16); }
DEV float sigm(float x){ return 1.f/(1.f+__expf(-x)); }
DEV int get_bf(const void* ln1g){ return ((*(const unsigned*)ln1g) & 0xFFFFu) == 0x3F80u; }

DEV float ld(const void* p, long i, int bf){
  return bf ? b2f(((const bf16*)p)[i]) : ((const float*)p)[i];
}
DEV void st(void* p, long i, float v, int bf){
  if (bf) ((bf16*)p)[i] = f2b(v); else ((float*)p)[i] = v;
}

constexpr float IMGX = 100.0f;
constexpr float IMGY = 56.0f;
constexpr float LOG_EPS = -15.942385f;
constexpr float BIN = 53.0f/1056.0f;
constexpr int NC = 25;
constexpr int CK = 224;

// ---- fp32 weight buffer offsets (floats) ----
constexpr int WO_SAQKVW = 0;
constexpr int WO_SAQKVB = 98304;
constexpr int WO_SAOW   = 99072;
constexpr int WO_SAOB   = 131840;
constexpr int WO_CAQKVW = 132096;
constexpr int WO_CAQKVB = 230400;
constexpr int WO_CAOW   = 231168;
constexpr int WO_CAOB   = 263936;
constexpr int WO_LN1G   = 264192;
constexpr int WO_LN1B   = 264448;
constexpr int WO_LN2G   = 264704;
constexpr int WO_LN2B   = 264960;
constexpr int WO_LN3G   = 265216;
constexpr int WO_LN3B   = 265472;
constexpr int WO_FW1    = 265728;
constexpr int WO_FB1    = 331264;
constexpr int WO_FW2    = 331776;
constexpr int WO_FB2    = 397312;
constexpr int WO_QW1    = 397568;
constexpr int WO_QB1    = 398080;
constexpr int WO_QW2    = 398336;
constexpr int WO_QB2    = 431104;
constexpr int WO_KW1    = 431360;
constexpr int WO_KB1    = 431872;
constexpr int WO_KB2    = 432128;
constexpr int WO_PW1    = 432384;
constexpr int WO_PB1    = 448768;
constexpr int WO_PW2    = 448896;
constexpr int WO_PB2    = 449664;
constexpr int W_TOTAL   = 449680;

// ---- workspace layout (floats) ----
constexpr size_t OFF_Q    = 0;        // 25600
constexpr size_t OFF_QPE  = 25600;
constexpr size_t OFF_QCA  = 51200;
constexpr size_t OFF_TMP  = 76800;    // 76800
constexpr size_t OFF_PM   = 153600;   // 40000
constexpr size_t OFF_PS   = 193600;   // 40000
constexpr size_t OFF_PO   = 233600;   // 640000
constexpr size_t OFF_FPOS = 873600;   // 11200
constexpr size_t OFF_CTR  = 884800;   // 400
constexpr size_t OFF_SIG  = 885200;   // 200
constexpr size_t OFF_QL   = 885400;   // ints: qcnt[8] + qlist[1200]
constexpr size_t OFF_WB   = 886624;
constexpr size_t F_TOTAL  = OFF_WB + W_TOTAL;
// bf16 region:
constexpr size_t B_KH   = 0;          // 4300800
constexpr size_t B_VH   = 4300800;
constexpr size_t B_WKVT = 8601600;    // 65536
constexpr size_t B_KW2T = 8667136;    // 32768

DEV void unpack2(unsigned u, float* f){ f[0]=u2f(u<<16); f[1]=u2f(u&0xffff0000u); }

template<int W>
DEV void mergeW(float& m, float& s, float (&o)[16]){
  #pragma unroll
  for (int off=W/2; off>=1; off>>=1){
    float m2 = __shfl_xor(m, off);
    float s2 = __shfl_xor(s, off);
    float mn = fmaxf(m, m2);
    float ea = (m  > -3.0e38f) ? __expf(m  - mn) : 0.f;
    float eb = (m2 > -3.0e38f) ? __expf(m2 - mn) : 0.f;
    s = s*ea + s2*eb;
    #pragma unroll
    for (int d=0; d<16; ++d){
      float od = __shfl_xor(o[d], off);
      o[d] = o[d]*ea + od*eb;
    }
    m = mn;
  }
}

DEV float wsum64(float v){
  #pragma unroll
  for (int off=32; off; off>>=1) v += __shfl_xor(v, off);
  return v;
}

// ================= weight conversion + qlist =================
struct Seg { const void* src; int off; int n; };
struct CvtArgs { Seg s[29]; };

__global__ void k_cvt(CvtArgs a, float* dst, int* qlp, const int* view, const void* ln1g){
  if (blockIdx.x == 29){
    int t = threadIdx.x;
    if (blockIdx.y == 0 && t < 6){
      int cnt = 0;
      for (int i = 0; i < 200; ++i)
        if (view[i] == t) qlp[8 + t*200 + cnt++] = i;
      qlp[t] = cnt;
    }
    return;
  }
  int bf = get_bf(ln1g);
  Seg sg = a.s[blockIdx.x];
  for (int i = blockIdx.y*blockDim.x + threadIdx.x; i < sg.n; i += gridDim.y*blockDim.x)
    dst[sg.off + i] = ld(sg.src, i, bf);
}

// weight transposes: ca_qkv K/V cols -> bf16 [l][n256][k]; kpos_w2 -> bf16 [l][c][k]
__global__ __launch_bounds__(128) void k_wT(const void* __restrict__ caw, const void* __restrict__ kw2,
                                            bf16* __restrict__ wkvT, bf16* __restrict__ kw2T,
                                            const void* __restrict__ ln1g){
  int bf = get_bf(ln1g);
  int c = blockIdx.x, l = blockIdx.y, k = threadIdx.x;
  if (c < 256){
    wkvT[((size_t)l*256 + c)*128 + k] = f2b(ld(caw, (long)l*49152 + (long)k*384 + 128 + c, bf));
  } else {
    int cc = c - 256;
    kw2T[((size_t)l*128 + cc)*128 + k] = f2b(ld(kw2, (long)l*16384 + (long)k*128 + cc, bf));
  }
}

// ================= prep2: centers/inverse/pos3d + q-init + pred0 sigma + fpos =================
__global__ __launch_bounds__(128) void k_prep2(
    const void* __restrict__ niqp, const void* __restrict__ l2i, const void* __restrict__ nifp,
    const int* __restrict__ view, const void* __restrict__ iqf,
    float* __restrict__ ctr, float* __restrict__ fpos, float* __restrict__ q,
    const float* __restrict__ wb, float* __restrict__ is2p,
    void* __restrict__ out, const void* __restrict__ ln1g){
  __shared__ float M[16];
  __shared__ float cs[2];
  __shared__ float xs[128];
  __shared__ float acc[6*128];
  __shared__ float bbv[8];
  int bf = get_bf(ln1g);
  int n = blockIdx.x, t = threadIdx.x;
  // fpos: 28 keys per block
  if (t < 28){
    int k = n*28 + t;
    fpos[2*k]   = sigm(ld(nifp,2*k,bf))*IMGX - 0.5f;
    fpos[2*k+1] = sigm(ld(nifp,2*k+1,bf))*IMGY - 0.5f;
  }
  // q init
  float xv = ld(iqf, (long)t*200 + n, bf);
  q[(size_t)n*128 + t] = xv;
  xs[t] = xv;
  if (t == 0){
    float p0 = ld(niqp,2*n,bf), p1 = ld(niqp,2*n+1,bf);
    float cx = sigm(p0)*IMGX, cy = sigm(p1)*IMGY;
    ctr[2*n] = cx; ctr[2*n+1] = cy;
    cs[0] = cx; cs[1] = cy;
    st(out, 25600 + 2*n,   p0, bf);
    st(out, 25600 + 2*n+1, p1, bf);
    int v = view[n];
    float a[4][8];
    for (int i=0;i<4;++i)
      for (int jj=0;jj<4;++jj){ a[i][jj] = ld(l2i, v*16+i*4+jj, bf); a[i][4+jj] = (i==jj)?1.f:0.f; }
    for (int col=0; col<4; ++col){
      int p = col; float best = fabsf(a[col][col]);
      for (int r=col+1;r<4;++r){ float tt=fabsf(a[r][col]); if (tt>best){best=tt;p=r;} }
      if (p!=col) for (int jj=0;jj<8;++jj){ float tt=a[col][jj]; a[col][jj]=a[p][jj]; a[p][jj]=tt; }
      float inv = 1.f/a[col][col];
      for (int jj=0;jj<8;++jj) a[col][jj]*=inv;
      for (int r=0;r<4;++r){
        if (r==col) continue;
        float f = a[r][col];
        for (int jj=0;jj<8;++jj) a[r][jj] -= f*a[col][jj];
      }
    }
    for (int i=0;i<4;++i) for (int jj=0;jj<4;++jj) M[i*4+jj] = a[i][4+jj];
  }
  __syncthreads();
  if (t < 32){
    int d = t;
    float px = cs[0]*8.f, py = cs[1]*8.f;
    float dep = 1.f + BIN * (float)d * (float)(d+1);
    float x = px*dep, y = py*dep;
    #pragma unroll
    for (int i=0;i<3;++i){
      float val = M[i*4]*x + M[i*4+1]*y + M[i*4+2]*dep + M[i*4+3];
      st(out, 26000 + n*96 + d*3 + i, val, bf);
    }
  }
  // pred0 for sigma
  float a = wb[WO_PB1 + t];
  const float* W = wb + WO_PW1;
  for (int k = 0; k < 128; ++k) a = fmaf(xs[k], W[k*128 + t], a);
  float x = fmaxf(a, 0.f);
  #pragma unroll
  for (int c=0;c<6;++c) acc[c*128+t] = x * wb[WO_PW2 + t*6 + c];
  __syncthreads();
  for (int off=64; off; off>>=1){
    if (t < off){
      #pragma unroll
      for (int c=0;c<6;++c) acc[c*128+t] += acc[c*128+t+off];
    }
    __syncthreads();
  }
  if (t < 6) bbv[t] = acc[t*128] + wb[WO_PB2 + t];
  __syncthreads();
  if (t == 0){
    float dxv = sigm(bbv[2]) * IMGX;
    float dyv = sigm(bbv[3]) * IMGY;
    float rad = ceilf(sqrtf(dxv*dxv + dyv*dyv) * 0.5f);
    float sg = (rad*2.f + 1.f) * (1.f/6.f);
    is2p[n] = 1.f/(2.f*sg*sg);
  }
}

// ================= fused kpe + K/V projection (MFMA) =================
// grid 525; computes kpe for its 64 rows in-LDS, adds iff (direct read), projects K/V.
__global__ __launch_bounds__(256) void k_kv(
    const void* __restrict__ nifp, const void* __restrict__ iff,
    const float* __restrict__ wb, int l,
    const bf16* __restrict__ kw2T, const bf16* __restrict__ wkvT,
    bf16* __restrict__ kh, bf16* __restrict__ vh, const void* __restrict__ ln1g){
  constexpr int XP = 136;
  __shared__ __align__(16) unsigned short hsb[64*XP];
  __shared__ __align__(16) unsigned short xs[64*XP];
  __shared__ float2 pr[64];
  int bf = get_bf(ln1g);
  int r0 = blockIdx.x * 64;
  int tid = threadIdx.x;
  if (tid < 64){
    int gr = r0 + tid;
    int k = gr % 5600;
    pr[tid] = make_float2(ld(nifp,2*k,bf), ld(nifp,2*k+1,bf));
  }
  __syncthreads();
  // hs = relu(pos@kw1 + kb1) as bf16
  const float* w1 = wb + WO_KW1 + l*256;
  const float* b1 = wb + WO_KB1 + l*128;
  for (int idx = tid; idx < 64*64; idx += 256){
    int r = idx >> 6, c2 = (idx & 63)*2;
    float2 p = pr[r];
    #pragma unroll
    for (int u=0;u<2;++u){
      int c = c2+u;
      float a = fmaf(p.x, w1[c], fmaf(p.y, w1[128+c], b1[c]));
      hsb[r*XP + c] = f2bu(fmaxf(a, 0.f));
    }
  }
  int wv = tid >> 6;
  int lane = tid & 63;
  int l16 = lane & 15, quad = lane >> 4;
  __syncthreads();
  // kpe MFMA: wave wv covers cols [32wv, 32wv+32) -> xs
  {
    f32x4 acc[4][2];
    #pragma unroll
    for (int mt=0;mt<4;++mt)
      #pragma unroll
      for (int nt=0;nt<2;++nt) acc[mt][nt] = (f32x4){0.f,0.f,0.f,0.f};
    #pragma unroll
    for (int kc = 0; kc < 4; ++kc){
      s16x8 bfr[2];
      #pragma unroll
      for (int nt = 0; nt < 2; ++nt){
        int col = wv*32 + nt*16 + l16;
        bfr[nt] = *(const s16x8*)&kw2T[((size_t)l*128 + col)*128 + kc*32 + quad*8];
      }
      s16x8 afr[4];
      #pragma unroll
      for (int mt = 0; mt < 4; ++mt)
        afr[mt] = *(const s16x8*)&hsb[(mt*16 + l16)*XP + kc*32 + quad*8];
      #pragma unroll
      for (int mt = 0; mt < 4; ++mt)
        #pragma unroll
        for (int nt = 0; nt < 2; ++nt)
          acc[mt][nt] = __builtin_amdgcn_mfma_f32_16x16x32_bf16(afr[mt], bfr[nt], acc[mt][nt], 0, 0, 0);
    }
    #pragma unroll
    for (int mt = 0; mt < 4; ++mt)
      #pragma unroll
      for (int i = 0; i < 4; ++i){
        int row = mt*16 + quad*4 + i;
        #pragma unroll
        for (int nt = 0; nt < 2; ++nt){
          int col = wv*32 + nt*16 + l16;
          xs[row*XP + col] = f2bu(acc[mt][nt][i] + wb[WO_KB2 + l*128 + col]);
        }
      }
  }
  __syncthreads();
  // add iff (keys) directly: coalesced over key index
  for (int idx = tid; idx < 64*128; idx += 256){
    int kk = idx & 63, c = idx >> 6;
    int gr = r0 + kk;
    int v = gr / 5600; int k = gr - v*5600;
    float kv = ld(iff, (long)(v*128 + c)*5600 + k, bf);
    xs[kk*XP + c] = f2bu(kv + bs2f(xs[kk*XP + c]));
  }
  __syncthreads();
  // main MFMA: wave wv covers out cols [64wv, 64wv+64)
  f32x4 acc[4][4];
  #pragma unroll
  for (int mt=0;mt<4;++mt)
    #pragma unroll
    for (int nt=0;nt<4;++nt) acc[mt][nt] = (f32x4){0.f,0.f,0.f,0.f};
  #pragma unroll
  for (int kc = 0; kc < 4; ++kc){
    s16x8 bfr[4];
    #pragma unroll
    for (int nt = 0; nt < 4; ++nt){
      int col = wv*64 + nt*16 + l16;
      bfr[nt] = *(const s16x8*)&wkvT[((size_t)l*256 + col)*128 + kc*32 + quad*8];
    }
    s16x8 afr[4];
    #pragma unroll
    for (int mt = 0; mt < 4; ++mt)
      afr[mt] = *(const s16x8*)&xs[(mt*16 + l16)*XP + kc*32 + quad*8];
    #pragma unroll
    for (int mt = 0; mt < 4; ++mt)
      #pragma unroll
      for (int nt = 0; nt < 4; ++nt)
        acc[mt][nt] = __builtin_amdgcn_mfma_f32_16x16x32_bf16(afr[mt], bfr[nt], acc[mt][nt], 0, 0, 0);
  }
  float bv[4];
  bf16* op[4];
  long ntOff[4];
  #pragma unroll
  for (int nt = 0; nt < 4; ++nt){
    int c = wv*64 + nt*16 + l16;
    bv[nt] = wb[WO_CAQKVB + l*384 + 128 + c];
    int sel = c >> 7, ch = c & 127;
    int h = ch >> 4, d = ch & 15;
    op[nt] = sel ? vh : kh;
    ntOff[nt] = (long)h*89600 + d;
  }
  #pragma unroll
  for (int mt = 0; mt < 4; ++mt)
    #pragma unroll
    for (int i = 0; i < 4; ++i){
      int gr = r0 + mt*16 + quad*4 + i;
      int v = gr / 5600; int k = gr - v*5600;
      long rowOff = (long)v*716800 + (long)k*16;
      #pragma unroll
      for (int nt = 0; nt < 4; ++nt)
        op[nt][rowOff + ntOff[nt]] = f2b(acc[mt][nt][i] + bv[nt]);
    }
}

// ================= fused qpe + sa_qkv projection =================
__global__ __launch_bounds__(384) void k_saqkv(
    const float* __restrict__ q, const void* __restrict__ niqp,
    const float* __restrict__ wb, int l,
    float* __restrict__ qpe_g, float* __restrict__ tmp, const void* __restrict__ ln1g){
  __shared__ float hs[128];
  __shared__ float xq[128];
  int bf = get_bf(ln1g);
  int n = blockIdx.x, t = threadIdx.x;
  if (t < 128){
    float p0 = ld(niqp,2*n,bf), p1 = ld(niqp,2*n+1,bf);
    float a = fmaf(p0, wb[WO_QW1 + l*256 + t], fmaf(p1, wb[WO_QW1 + l*256 + 128 + t], wb[WO_QB1 + l*128 + t]));
    hs[t] = fmaxf(a, 0.f);
  }
  __syncthreads();
  if (t < 128){
    const float* W = wb + WO_QW2 + l*16384;
    float a = wb[WO_QB2 + l*128 + t];
    for (int k = 0; k < 128; ++k) a = fmaf(hs[k], W[k*128 + t], a);
    qpe_g[(size_t)n*128 + t] = a;
    xq[t] = q[(size_t)n*128 + t] + a;
  }
  __syncthreads();
  const float* W = wb + WO_SAQKVW + l*49152;
  float acc = wb[WO_SAQKVB + l*384 + t];
  for (int k = 0; k < 128; ++k) acc = fmaf(xq[k], W[k*384 + t], acc);
  tmp[(size_t)n*384 + t] = acc;
}

// ================= self-attn + out-proj + LN1 + ca-q projection =================
__global__ __launch_bounds__(128) void k_self_attn_f(
    const float* __restrict__ qkv, const int* __restrict__ view,
    const float* __restrict__ wb, int l,
    float* __restrict__ q, const float* __restrict__ qpe_g, float* __restrict__ qca){
  __shared__ float att[128];
  __shared__ float red[128];
  __shared__ float xs2[128];
  int n = blockIdx.x, t = threadIdx.x;
  int h = t >> 4, j = t & 15;
  int vn = view[n];
  float qh[16];
  #pragma unroll
  for (int d=0; d<16; ++d) qh[d] = qkv[(size_t)n*384 + h*16 + d] * 0.25f;
  float m = -INFINITY, s = 0.f, o[16];
  #pragma unroll
  for (int d=0; d<16; ++d) o[d]=0.f;
  for (int k = j; k < 200; k += 16){
    float l2;
    if (view[k] != vn){ l2 = -INFINITY; }
    else {
      const float* kr = qkv + (size_t)k*384 + 128 + h*16;
      l2 = 0.f;
      #pragma unroll
      for (int d=0; d<16; ++d) l2 = fmaf(qh[d], kr[d], l2);
    }
    float mn = fmaxf(m, l2);
    float ea = (m > -3.0e38f) ? __expf(m - mn) : 0.f;
    float p  = (l2 > -3.0e38f) ? __expf(l2 - mn) : 0.f;
    s = s*ea + p;
    const float* vr = qkv + (size_t)k*384 + 256 + h*16;
    #pragma unroll
    for (int d=0; d<16; ++d) o[d] = o[d]*ea + p*vr[d];
    m = mn;
  }
  mergeW<16>(m, s, o);
  if (j == 0){
    float inv = (s > 0.f) ? 1.f/s : 0.f;
    #pragma unroll
    for (int d=0; d<16; ++d) att[h*16 + d] = o[d]*inv;
  }
  __syncthreads();
  const float* W = wb + WO_SAOW + l*16384;
  float acc = wb[WO_SAOB + l*128 + t];
  for (int k = 0; k < 128; ++k) acc = fmaf(att[k], W[k*128 + t], acc);
  float v = q[(size_t)n*128 + t] + acc;
  red[t] = v; __syncthreads();
  for (int off=64; off; off>>=1){ if (t<off) red[t]+=red[t+off]; __syncthreads(); }
  float mean = red[0]*(1.f/128.f);
  __syncthreads();
  float d = v - mean;
  red[t] = d*d; __syncthreads();
  for (int off=64; off; off>>=1){ if (t<off) red[t]+=red[t+off]; __syncthreads(); }
  float var = red[0]*(1.f/128.f);
  float r = rsqrtf(var + 1e-5f);
  float qn = d*r*wb[WO_LN1G + l*128 + t] + wb[WO_LN1B + l*128 + t];
  q[(size_t)n*128 + t] = qn;
  xs2[t] = qn + qpe_g[(size_t)n*128 + t];
  __syncthreads();
  const float* Wc = wb + WO_CAQKVW + l*49152;
  float a2 = wb[WO_CAQKVB + l*384 + t];
  for (int k = 0; k < 128; ++k) a2 = fmaf(xs2[k], Wc[k*384 + t], a2);
  qca[(size_t)n*128 + t] = a2;
}

// ================= cross-attention partial: fp32 LDS K/V =================
// grid (NC, 8, 6), block 256 = 8 groups of 32 lanes
__global__ __launch_bounds__(256) void k_cross_part(
    const float* __restrict__ qca, const bf16* __restrict__ kh, const bf16* __restrict__ vh,
    const float* __restrict__ fpos, const float* __restrict__ ctr,
    const float* __restrict__ is2p, const int* __restrict__ qlp,
    float* __restrict__ pm, float* __restrict__ ps, float* __restrict__ po){
  __shared__ __align__(8) float KS[CK*18];
  __shared__ __align__(8) float VS[CK*18];
  __shared__ float2 fp[CK];
  int ch = blockIdx.x, h = blockIdx.y, v = blockIdx.z;
  int t = threadIdx.x;
  int k0 = ch*CK;
  const uint2* ks = (const uint2*)(kh + ((size_t)(v*8 + h)*5600 + k0)*16);
  const uint2* vs = (const uint2*)(vh + ((size_t)(v*8 + h)*5600 + k0)*16);
  for (int i = t; i < CK*4; i += 256){
    int key = i >> 2, part = i & 3;
    float f[4];
    uint2 a = ks[i]; unpack2(a.x, f); unpack2(a.y, f+2);
    *(float2*)&KS[key*18 + part*4]     = make_float2(f[0],f[1]);
    *(float2*)&KS[key*18 + part*4 + 2] = make_float2(f[2],f[3]);
    uint2 b = vs[i]; unpack2(b.x, f); unpack2(b.y, f+2);
    *(float2*)&VS[key*18 + part*4]     = make_float2(f[0],f[1]);
    *(float2*)&VS[key*18 + part*4 + 2] = make_float2(f[2],f[3]);
  }
  if (t < CK) fp[t] = ((const float2*)fpos)[k0 + t];
  __syncthreads();
  int nq = qlp[v];
  const int* ql = qlp + 8 + v*200;
  int g = t >> 5, j = t & 31;
  for (int p = g; p < nq; p += 8){
    int n = ql[p];
    float cx = ctr[2*n], cy = ctr[2*n+1];
    float is2 = is2p[n];
    float qh[16];
    const float* qrow = qca + (size_t)n*128 + h*16;
    #pragma unroll
    for (int d=0; d<16; ++d) qh[d] = qrow[d] * 0.25f;
    float m = -INFINITY, s = 0.f, o[16];
    #pragma unroll
    for (int d=0; d<16; ++d) o[d]=0.f;
    #pragma unroll
    for (int i = 0; i < CK/32; ++i){
      int key = i*32 + j;
      float2 pxy = fp[key];
      float dx = cx - pxy.x, dy = cy - pxy.y;
      float gg = -(dx*dx + dy*dy) * is2;
      const float2* kp = (const float2*)&KS[key*18];
      const float2* vp = (const float2*)&VS[key*18];
      float l = gg;
      float vf[16];
      #pragma unroll
      for (int u=0; u<8; ++u){
        float2 kk = kp[u];
        l = fmaf(qh[2*u], kk.x, fmaf(qh[2*u+1], kk.y, l));
        float2 vv = vp[u];
        vf[2*u] = vv.x; vf[2*u+1] = vv.y;
      }
      l = (gg < LOG_EPS) ? -INFINITY : l;
      float mn = fmaxf(m, l);
      float ea = (m > -3.0e38f) ? __expf(m - mn) : 0.f;
      float pr = (l > -3.0e38f) ? __expf(l - mn) : 0.f;
      s = s*ea + pr;
      #pragma unroll
      for (int d=0; d<16; ++d) o[d] = o[d]*ea + pr*vf[d];
      m = mn;
    }
    // max-first merge: reduce max, rescale once, then plain-add butterflies
    float M = m;
    #pragma unroll
    for (int off=16; off>=1; off>>=1) M = fmaxf(M, __shfl_xor(M, off));
    float sc = (m > -3.0e38f) ? __expf(m - M) : 0.f;
    s *= sc;
    #pragma unroll
    for (int d=0; d<16; ++d) o[d] *= sc;
    #pragma unroll
    for (int off=16; off>=1; off>>=1){
      s += __shfl_xor(s, off);
      #pragma unroll
      for (int d=0; d<16; ++d) o[d] += __shfl_xor(o[d], off);
    }
    if (j == 0){
      int idx = (n*NC + ch)*8 + h;
      pm[idx] = M; ps[idx] = s;
      float4* o4 = (float4*)(po + (size_t)idx*16);
      o4[0] = make_float4(o[0],o[1],o[2],o[3]);
      o4[1] = make_float4(o[4],o[5],o[6],o[7]);
      o4[2] = make_float4(o[8],o[9],o[10],o[11]);
      o4[3] = make_float4(o[12],o[13],o[14],o[15]);
    }
  }
}

// ================= tail =================
__global__ __launch_bounds__(256) void k_tail(
    const float* __restrict__ pm, const float* __restrict__ ps, const float* __restrict__ po,
    const float* __restrict__ wb, int l, float* __restrict__ q,
    const void* __restrict__ niqp, void* __restrict__ out, long outOff,
    float* __restrict__ is2p, int last, const void* __restrict__ ln1g){
  __shared__ float att[128];
  __shared__ float sm[2][128], ss[2][128], so[2][128];
  __shared__ float part[256];
  __shared__ float redw[4];
  __shared__ float xs[128];
  __shared__ float hs[256];
  __shared__ float ac6[6*128];
  __shared__ float bbv[8];
  int bf = get_bf(ln1g);
  int n = blockIdx.x, t = threadIdx.x;
  int tc = t & 127, half = t >> 7;
  {
    int h = tc >> 4, d = tc & 15;
    int c0 = half ? 12 : 0, c1 = half ? NC : 12;
    float m = -INFINITY, s = 0.f, o = 0.f;
    for (int c = c0; c < c1; ++c){
      int idx = (n*NC + c)*8 + h;
      float mc = pm[idx], sc = ps[idx], oc = po[(size_t)idx*16 + d];
      float mn = fmaxf(m, mc);
      float ea = (m  > -3.0e38f) ? __expf(m  - mn) : 0.f;
      float eb = (mc > -3.0e38f) ? __expf(mc - mn) : 0.f;
      s = s*ea + sc*eb;
      o = o*ea + oc*eb;
      m = mn;
    }
    sm[half][tc]=m; ss[half][tc]=s; so[half][tc]=o;
  }
  __syncthreads();
  if (t < 128){
    float m1=sm[0][t], m2=sm[1][t];
    float mn=fmaxf(m1,m2);
    float e1=(m1>-3.0e38f)?__expf(m1-mn):0.f, e2=(m2>-3.0e38f)?__expf(m2-mn):0.f;
    float s = ss[0][t]*e1 + ss[1][t]*e2;
    float o = so[0][t]*e1 + so[1][t]*e2;
    att[t] = (s>0.f)? o/s : 0.f;
  }
  __syncthreads();
  {
    const float* W = wb + WO_CAOW + l*16384;
    float a = 0.f;
    for (int k = half*64; k < half*64+64; ++k) a = fmaf(att[k], W[k*128 + tc], a);
    part[t] = a;
  }
  __syncthreads();
  float v = (t<128) ? q[(size_t)n*128 + t] + part[t] + part[128+t] + wb[WO_CAOB + l*128 + t] : 0.f;
  float sv = wsum64(v);
  if ((t&63)==0) redw[t>>6] = sv;
  __syncthreads();
  float mean = (redw[0]+redw[1]+redw[2]+redw[3]) * (1.f/128.f);
  __syncthreads();
  float d = (t<128)? v-mean : 0.f;
  sv = wsum64(d*d);
  if ((t&63)==0) redw[t>>6] = sv;
  __syncthreads();
  float var = (redw[0]+redw[1]+redw[2]+redw[3]) * (1.f/128.f);
  float r = rsqrtf(var + 1e-5f);
  if (t<128) xs[t] = d*r*wb[WO_LN2G + l*128 + t] + wb[WO_LN2B + l*128 + t];
  __syncthreads();
  {
    const float* W = wb + WO_FW1 + l*32768;
    float a = wb[WO_FB1 + l*256 + t];
    for (int k=0;k<128;++k) a = fmaf(xs[k], W[k*256 + t], a);
    hs[t] = fmaxf(a, 0.f);
  }
  __syncthreads();
  {
    const float* W = wb + WO_FW2 + l*32768;
    float a = 0.f;
    for (int k=half*128;k<half*128+128;++k) a = fmaf(hs[k], W[k*128 + tc], a);
    part[t] = a;
  }
  __syncthreads();
  v = (t<128) ? xs[t] + part[t] + part[128+t] + wb[WO_FB2 + l*128 + t] : 0.f;
  sv = wsum64(v);
  if ((t&63)==0) redw[t>>6] = sv;
  __syncthreads();
  mean = (redw[0]+redw[1]+redw[2]+redw[3]) * (1.f/128.f);
  __syncthreads();
  d = (t<128)? v-mean : 0.f;
  sv = wsum64(d*d);
  if ((t&63)==0) redw[t>>6] = sv;
  __syncthreads();
  var = (redw[0]+redw[1]+redw[2]+redw[3]) * (1.f/128.f);
  r = rsqrtf(var + 1e-5f);
  if (t<128){
    float q3 = d*r*wb[WO_LN3G + l*128 + t] + wb[WO_LN3B + l*128 + t];
    q[(size_t)n*128 + t] = q3;
    xs[t] = q3;
    if (last) st(out, (long)t*200 + n, q3, bf);
  }
  __syncthreads();
  {
    const float* W = wb + WO_PW1;
    float a = 0.f;
    for (int k=half*64;k<half*64+64;++k) a = fmaf(xs[k], W[k*128 + tc], a);
    part[t] = a;
  }
  __syncthreads();
  if (t<128){
    float x = fmaxf(part[t] + part[128+t] + wb[WO_PB1 + t], 0.f);
    #pragma unroll
    for (int c=0;c<6;++c) ac6[c*128+t] = x * wb[WO_PW2 + t*6 + c];
  }
  __syncthreads();
  for (int off=64; off; off>>=1){
    if (t < off){
      #pragma unroll
      for (int c=0;c<6;++c) ac6[c*128+t] += ac6[c*128+t+off];
    }
    __syncthreads();
  }
  if (t < 6){
    float raw = ac6[t*128] + wb[WO_PB2 + t];
    if (t < 2) raw += ld(niqp, 2*n + t, bf);
    float svv = sigm(raw);
    st(out, outOff + n*6 + t, svv, bf);
    bbv[t] = svv;
  }
  __syncthreads();
  if (t == 0){
    float dxv = sigm(bbv[2]) * IMGX;
    float dyv = sigm(bbv[3]) * IMGY;
    float rad = ceilf(sqrtf(dxv*dxv + dyv*dyv) * 0.5f);
    float sg = (rad*2.f + 1.f) * (1.f/6.f);
    is2p[n] = 1.f/(2.f*sg*sg);
  }
}

// ================= launch =================
extern "C" void kernel_launch(void* const* d_in, const int* in_sizes, int n_in,
                              void* d_out, int out_size, void* d_ws, size_t ws_size,
                              hipStream_t stream){
  const void* iqf   = d_in[0];
  const void* niqp  = d_in[1];
  const void* iff   = d_in[2];
  const void* nifp  = d_in[3];
  const void* l2i   = d_in[4];
  const int*  view  = (const int*)d_in[5];
  const void* ln1_g = d_in[14];

  float* fw = (float*)d_ws;
  float* q    = fw + OFF_Q;
  float* qpe  = fw + OFF_QPE;
  float* qca  = fw + OFF_QCA;
  float* tmp  = fw + OFF_TMP;
  float* pm   = fw + OFF_PM;
  float* ps   = fw + OFF_PS;
  float* po   = fw + OFF_PO;
  float* fpos = fw + OFF_FPOS;
  float* ctr  = fw + OFF_CTR;
  float* sig2 = fw + OFF_SIG;
  int*   qlp  = (int*)(fw + OFF_QL);
  float* wb   = fw + OFF_WB;
  bf16* bw   = (bf16*)((char*)d_ws + F_TOTAL*sizeof(float));
  bf16* kh   = bw + B_KH;
  bf16* vh   = bw + B_VH;
  bf16* wkvT = bw + B_WKVT;
  bf16* kw2T = bw + B_KW2T;

  CvtArgs ca;
  ca.s[0]  = {d_in[6],  WO_SAQKVW, 98304};
  ca.s[1]  = {d_in[7],  WO_SAQKVB, 768};
  ca.s[2]  = {d_in[8],  WO_SAOW,   32768};
  ca.s[3]  = {d_in[9],  WO_SAOB,   256};
  ca.s[4]  = {d_in[10], WO_CAQKVW, 98304};
  ca.s[5]  = {d_in[11], WO_CAQKVB, 768};
  ca.s[6]  = {d_in[12], WO_CAOW,   32768};
  ca.s[7]  = {d_in[13], WO_CAOB,   256};
  ca.s[8]  = {d_in[14], WO_LN1G,   256};
  ca.s[9]  = {d_in[15], WO_LN1B,   256};
  ca.s[10] = {d_in[16], WO_LN2G,   256};
  ca.s[11] = {d_in[17], WO_LN2B,   256};
  ca.s[12] = {d_in[18], WO_LN3G,   256};
  ca.s[13] = {d_in[19], WO_LN3B,   256};
  ca.s[14] = {d_in[20], WO_FW1,    65536};
  ca.s[15] = {d_in[21], WO_FB1,    512};
  ca.s[16] = {d_in[22], WO_FW2,    65536};
  ca.s[17] = {d_in[23], WO_FB2,    256};
  ca.s[18] = {d_in[24], WO_QW1,    512};
  ca.s[19] = {d_in[25], WO_QB1,    256};
  ca.s[20] = {d_in[26], WO_QW2,    32768};
  ca.s[21] = {d_in[27], WO_QB2,    256};
  ca.s[22] = {d_in[28], WO_KW1,    512};
  ca.s[23] = {d_in[29], WO_KB1,    256};
  ca.s[24] = {d_in[31], WO_KB2,    256};
  ca.s[25] = {d_in[32], WO_PW1,    16384};
  ca.s[26] = {d_in[33], WO_PB1,    128};
  ca.s[27] = {d_in[34], WO_PW2,    768};
  ca.s[28] = {d_in[35], WO_PB2,    6};

  k_cvt<<<dim3(30,8), 256, 0, stream>>>(ca, wb, qlp, view, ln1_g);
  k_wT<<<dim3(384,2), 128, 0, stream>>>(d_in[10], d_in[30], wkvT, kw2T, ln1_g);
  k_prep2<<<200, 128, 0, stream>>>(niqp, l2i, nifp, view, iqf, ctr, fpos, q, wb, sig2, d_out, ln1_g);

  for (int l = 0; l < 2; ++l){
    k_kv<<<525, 256, 0, stream>>>(nifp, iff, wb, l, kw2T, wkvT, kh, vh, ln1_g);
    k_saqkv<<<200, 384, 0, stream>>>(q, niqp, wb, l, qpe, tmp, ln1_g);
    k_self_attn_f<<<200, 128, 0, stream>>>(tmp, view, wb, l, q, qpe, qca);
    k_cross_part<<<dim3(NC,8,6), 256, 0, stream>>>(qca, kh, vh, fpos, ctr, sig2, qlp, pm, ps, po);
    k_tail<<<200, 256, 0, stream>>>(pm, ps, po, wb, l, q, niqp, d_out,
                                    (l==0 ? 45200L : 46400L), sig2, (l==1) ? 1 : 0, ln1_g);
  }
}

// Round 9
// 484.128 us; speedup vs baseline: 1.1245x; 1.1245x over previous
//
#include <hip/hip_runtime.h>
#include <hip/hip_bf16.h>
#include <cstdint>
#include <cstddef>

using bf16 = __hip_bfloat16;
#define DEV __device__ __forceinline__

typedef short s16x8 __attribute__((ext_vector_type(8)));
typedef float f32x4 __attribute__((ext_vector_type(4)));

DEV float b2f(bf16 x){ return __bfloat162float(x); }
DEV bf16  f2b(float x){ return __float2bfloat16(x); }
DEV float u2f(unsigned u){ union{unsigned u; float f;} c; c.u=u; return c.f; }
DEV unsigned f2u(float f){ union{float f; unsigned u;} c; c.f=f; return c.u; }
DEV unsigned short f2bu(float f){ unsigned u = f2u(f); u += 0x7FFFu + ((u>>16)&1u); return (unsigned short)(u>>16); }
DEV float bs2f(unsigned short s){ return u2f(((unsigned)s)<<16); }
DEV float sigm(float x){ return 1.f/(1.f+__expf(-x)); }
DEV int get_bf(const void* ln1g){ return ((*(const unsigned*)ln1g) & 0xFFFFu) == 0x3F80u; }

DEV float ld(const void* p, long i, int bf){
  return bf ? b2f(((const bf16*)p)[i]) : ((const float*)p)[i];
}
DEV void st(void* p, long i, float v, int bf){
  if (bf) ((bf16*)p)[i] = f2b(v); else ((float*)p)[i] = v;
}

constexpr float IMGX = 100.0f;
constexpr float IMGY = 56.0f;
constexpr float LOG_EPS = -15.942385f;
constexpr float BIN = 53.0f/1056.0f;
constexpr int NC = 35;
constexpr int CK = 160;

// ---- fp32 weight buffer offsets (floats) ----
constexpr int WO_SAQKVW = 0;
constexpr int WO_SAQKVB = 98304;
constexpr int WO_SAOW   = 99072;
constexpr int WO_SAOB   = 131840;
constexpr int WO_CAQKVW = 132096;
constexpr int WO_CAQKVB = 230400;
constexpr int WO_CAOW   = 231168;
constexpr int WO_CAOB   = 263936;
constexpr int WO_LN1G   = 264192;
constexpr int WO_LN1B   = 264448;
constexpr int WO_LN2G   = 264704;
constexpr int WO_LN2B   = 264960;
constexpr int WO_LN3G   = 265216;
constexpr int WO_LN3B   = 265472;
constexpr int WO_FW1    = 265728;
constexpr int WO_FB1    = 331264;
constexpr int WO_FW2    = 331776;
constexpr int WO_FB2    = 397312;
constexpr int WO_QW1    = 397568;
constexpr int WO_QB1    = 398080;
constexpr int WO_QW2    = 398336;
constexpr int WO_QB2    = 431104;
constexpr int WO_KW1    = 431360;
constexpr int WO_KB1    = 431872;
constexpr int WO_KB2    = 432128;
constexpr int WO_PW1    = 432384;
constexpr int WO_PB1    = 448768;
constexpr int WO_PW2    = 448896;
constexpr int WO_PB2    = 449664;
constexpr int W_TOTAL   = 449680;

// ---- workspace layout (floats) ----
constexpr size_t OFF_Q    = 0;
constexpr size_t OFF_QPE  = 25600;
constexpr size_t OFF_QCA  = 51200;
constexpr size_t OFF_TMP  = 76800;
constexpr size_t OFF_PM   = 153600;   // 56000
constexpr size_t OFF_PS   = 209600;   // 56000
constexpr size_t OFF_PO   = 265600;   // 896000
constexpr size_t OFF_FPOS = 1161600;  // 11200
constexpr size_t OFF_CTR  = 1172800;
constexpr size_t OFF_SIG  = 1173200;
constexpr size_t OFF_QL   = 1173400;  // 1216 ints
constexpr size_t OFF_WB   = 1174624;
constexpr size_t F_TOTAL  = OFF_WB + W_TOTAL;
// bf16 region:
constexpr size_t B_KH   = 0;
constexpr size_t B_VH   = 4300800;
constexpr size_t B_WKVT = 8601600;
constexpr size_t B_KW2T = 8667136;

DEV void unpack2(unsigned u, float* f){ f[0]=u2f(u<<16); f[1]=u2f(u&0xffff0000u); }

template<int W>
DEV void mergeW(float& m, float& s, float (&o)[16]){
  #pragma unroll
  for (int off=W/2; off>=1; off>>=1){
    float m2 = __shfl_xor(m, off);
    float s2 = __shfl_xor(s, off);
    float mn = fmaxf(m, m2);
    float ea = (m  > -3.0e38f) ? __expf(m  - mn) : 0.f;
    float eb = (m2 > -3.0e38f) ? __expf(m2 - mn) : 0.f;
    s = s*ea + s2*eb;
    #pragma unroll
    for (int d=0; d<16; ++d){
      float od = __shfl_xor(o[d], off);
      o[d] = o[d]*ea + od*eb;
    }
    m = mn;
  }
}

DEV float wsum64(float v){
  #pragma unroll
  for (int off=32; off; off>>=1) v += __shfl_xor(v, off);
  return v;
}

// ================= weight conversion + qlist =================
struct Seg { const void* src; int off; int n; };
struct CvtArgs { Seg s[29]; };

__global__ void k_cvt(CvtArgs a, float* dst, int* qlp, const int* view, const void* ln1g){
  if (blockIdx.x == 29){
    int t = threadIdx.x;
    if (blockIdx.y == 0 && t < 6){
      int cnt = 0;
      for (int i = 0; i < 200; ++i)
        if (view[i] == t) qlp[8 + t*200 + cnt++] = i;
      qlp[t] = cnt;
    }
    return;
  }
  int bf = get_bf(ln1g);
  Seg sg = a.s[blockIdx.x];
  for (int i = blockIdx.y*blockDim.x + threadIdx.x; i < sg.n; i += gridDim.y*blockDim.x)
    dst[sg.off + i] = ld(sg.src, i, bf);
}

__global__ __launch_bounds__(128) void k_wT(const void* __restrict__ caw, const void* __restrict__ kw2,
                                            bf16* __restrict__ wkvT, bf16* __restrict__ kw2T,
                                            const void* __restrict__ ln1g){
  int bf = get_bf(ln1g);
  int c = blockIdx.x, l = blockIdx.y, k = threadIdx.x;
  if (c < 256){
    wkvT[((size_t)l*256 + c)*128 + k] = f2b(ld(caw, (long)l*49152 + (long)k*384 + 128 + c, bf));
  } else {
    int cc = c - 256;
    kw2T[((size_t)l*128 + cc)*128 + k] = f2b(ld(kw2, (long)l*16384 + (long)k*128 + cc, bf));
  }
}

// ================= prep2 =================
__global__ __launch_bounds__(128) void k_prep2(
    const void* __restrict__ niqp, const void* __restrict__ l2i, const void* __restrict__ nifp,
    const int* __restrict__ view, const void* __restrict__ iqf,
    float* __restrict__ ctr, float* __restrict__ fpos, float* __restrict__ q,
    const float* __restrict__ wb, float* __restrict__ is2p,
    void* __restrict__ out, const void* __restrict__ ln1g){
  __shared__ float M[16];
  __shared__ float cs[2];
  __shared__ float xs[128];
  __shared__ float acc[6*128];
  __shared__ float bbv[8];
  int bf = get_bf(ln1g);
  int n = blockIdx.x, t = threadIdx.x;
  if (t < 28){
    int k = n*28 + t;
    fpos[2*k]   = sigm(ld(nifp,2*k,bf))*IMGX - 0.5f;
    fpos[2*k+1] = sigm(ld(nifp,2*k+1,bf))*IMGY - 0.5f;
  }
  float xv = ld(iqf, (long)t*200 + n, bf);
  q[(size_t)n*128 + t] = xv;
  xs[t] = xv;
  if (t == 0){
    float p0 = ld(niqp,2*n,bf), p1 = ld(niqp,2*n+1,bf);
    float cx = sigm(p0)*IMGX, cy = sigm(p1)*IMGY;
    ctr[2*n] = cx; ctr[2*n+1] = cy;
    cs[0] = cx; cs[1] = cy;
    st(out, 25600 + 2*n,   p0, bf);
    st(out, 25600 + 2*n+1, p1, bf);
    int v = view[n];
    float a[4][8];
    for (int i=0;i<4;++i)
      for (int jj=0;jj<4;++jj){ a[i][jj] = ld(l2i, v*16+i*4+jj, bf); a[i][4+jj] = (i==jj)?1.f:0.f; }
    for (int col=0; col<4; ++col){
      int p = col; float best = fabsf(a[col][col]);
      for (int r=col+1;r<4;++r){ float tt=fabsf(a[r][col]); if (tt>best){best=tt;p=r;} }
      if (p!=col) for (int jj=0;jj<8;++jj){ float tt=a[col][jj]; a[col][jj]=a[p][jj]; a[p][jj]=tt; }
      float inv = 1.f/a[col][col];
      for (int jj=0;jj<8;++jj) a[col][jj]*=inv;
      for (int r=0;r<4;++r){
        if (r==col) continue;
        float f = a[r][col];
        for (int jj=0;jj<8;++jj) a[r][jj] -= f*a[col][jj];
      }
    }
    for (int i=0;i<4;++i) for (int jj=0;jj<4;++jj) M[i*4+jj] = a[i][4+jj];
  }
  __syncthreads();
  if (t < 32){
    int d = t;
    float px = cs[0]*8.f, py = cs[1]*8.f;
    float dep = 1.f + BIN * (float)d * (float)(d+1);
    float x = px*dep, y = py*dep;
    #pragma unroll
    for (int i=0;i<3;++i){
      float val = M[i*4]*x + M[i*4+1]*y + M[i*4+2]*dep + M[i*4+3];
      st(out, 26000 + n*96 + d*3 + i, val, bf);
    }
  }
  float a = wb[WO_PB1 + t];
  const float* W = wb + WO_PW1;
  for (int k = 0; k < 128; ++k) a = fmaf(xs[k], W[k*128 + t], a);
  float x = fmaxf(a, 0.f);
  #pragma unroll
  for (int c=0;c<6;++c) acc[c*128+t] = x * wb[WO_PW2 + t*6 + c];
  __syncthreads();
  for (int off=64; off; off>>=1){
    if (t < off){
      #pragma unroll
      for (int c=0;c<6;++c) acc[c*128+t] += acc[c*128+t+off];
    }
    __syncthreads();
  }
  if (t < 6) bbv[t] = acc[t*128] + wb[WO_PB2 + t];
  __syncthreads();
  if (t == 0){
    float dxv = sigm(bbv[2]) * IMGX;
    float dyv = sigm(bbv[3]) * IMGY;
    float rad = ceilf(sqrtf(dxv*dxv + dyv*dyv) * 0.5f);
    float sg = (rad*2.f + 1.f) * (1.f/6.f);
    is2p[n] = 1.f/(2.f*sg*sg);
  }
}

// ================= fused wide kernel: [0,525) kv-projection MFMA, [525,725) qpe+sa_qkv =================
__global__ __launch_bounds__(384) void k_kvq(
    const void* __restrict__ nifp, const void* __restrict__ iff, const void* __restrict__ niqp,
    const float* __restrict__ q, const float* __restrict__ wb, int l,
    const bf16* __restrict__ kw2T, const bf16* __restrict__ wkvT,
    bf16* __restrict__ kh, bf16* __restrict__ vh,
    float* __restrict__ qpe_g, float* __restrict__ tmp, const void* __restrict__ ln1g){
  constexpr int XP = 136;
  __shared__ __align__(16) unsigned short hsb[64*XP];
  __shared__ __align__(16) unsigned short xs[64*XP];
  __shared__ float2 pr[64];
  int bf = get_bf(ln1g);
  int b = blockIdx.x;
  int tid = threadIdx.x;
  if (b >= 525){
    // ---- saqkv path ----
    float* hs = (float*)hsb;        // 128 floats
    float* xq = hs + 128;           // 128 floats
    int n = b - 525, t = tid;
    if (t < 128){
      float p0 = ld(niqp,2*n,bf), p1 = ld(niqp,2*n+1,bf);
      float a = fmaf(p0, wb[WO_QW1 + l*256 + t], fmaf(p1, wb[WO_QW1 + l*256 + 128 + t], wb[WO_QB1 + l*128 + t]));
      hs[t] = fmaxf(a, 0.f);
    }
    __syncthreads();
    if (t < 128){
      const float* W = wb + WO_QW2 + l*16384;
      float a = wb[WO_QB2 + l*128 + t];
      for (int k = 0; k < 128; ++k) a = fmaf(hs[k], W[k*128 + t], a);
      qpe_g[(size_t)n*128 + t] = a;
      xq[t] = q[(size_t)n*128 + t] + a;
    }
    __syncthreads();
    const float* W = wb + WO_SAQKVW + l*49152;
    float acc = wb[WO_SAQKVB + l*384 + t];
    for (int k = 0; k < 128; ++k) acc = fmaf(xq[k], W[k*384 + t], acc);
    tmp[(size_t)n*384 + t] = acc;
    return;
  }
  // ---- kv path ----
  int r0 = b * 64;
  if (tid < 64){
    int gr = r0 + tid;
    int k = gr % 5600;
    pr[tid] = make_float2(ld(nifp,2*k,bf), ld(nifp,2*k+1,bf));
  }
  __syncthreads();
  const float* w1 = wb + WO_KW1 + l*256;
  const float* b1 = wb + WO_KB1 + l*128;
  for (int idx = tid; idx < 64*64; idx += 384){
    int r = idx >> 6, c2 = (idx & 63)*2;
    float2 p = pr[r];
    #pragma unroll
    for (int u=0;u<2;++u){
      int c = c2+u;
      float a = fmaf(p.x, w1[c], fmaf(p.y, w1[128+c], b1[c]));
      hsb[r*XP + c] = f2bu(fmaxf(a, 0.f));
    }
  }
  int wv = tid >> 6;
  int lane = tid & 63;
  int l16 = lane & 15, quad = lane >> 4;
  __syncthreads();
  if (tid < 256){
    f32x4 acc[4][2];
    #pragma unroll
    for (int mt=0;mt<4;++mt)
      #pragma unroll
      for (int nt=0;nt<2;++nt) acc[mt][nt] = (f32x4){0.f,0.f,0.f,0.f};
    #pragma unroll
    for (int kc = 0; kc < 4; ++kc){
      s16x8 bfr[2];
      #pragma unroll
      for (int nt = 0; nt < 2; ++nt){
        int col = wv*32 + nt*16 + l16;
        bfr[nt] = *(const s16x8*)&kw2T[((size_t)l*128 + col)*128 + kc*32 + quad*8];
      }
      s16x8 afr[4];
      #pragma unroll
      for (int mt = 0; mt < 4; ++mt)
        afr[mt] = *(const s16x8*)&hsb[(mt*16 + l16)*XP + kc*32 + quad*8];
      #pragma unroll
      for (int mt = 0; mt < 4; ++mt)
        #pragma unroll
        for (int nt = 0; nt < 2; ++nt)
          acc[mt][nt] = __builtin_amdgcn_mfma_f32_16x16x32_bf16(afr[mt], bfr[nt], acc[mt][nt], 0, 0, 0);
    }
    #pragma unroll
    for (int mt = 0; mt < 4; ++mt)
      #pragma unroll
      for (int i = 0; i < 4; ++i){
        int row = mt*16 + quad*4 + i;
        #pragma unroll
        for (int nt = 0; nt < 2; ++nt){
          int col = wv*32 + nt*16 + l16;
          xs[row*XP + col] = f2bu(acc[mt][nt][i] + wb[WO_KB2 + l*128 + col]);
        }
      }
  }
  __syncthreads();
  for (int idx = tid; idx < 64*128; idx += 384){
    int kk = idx & 63, c = idx >> 6;
    int gr = r0 + kk;
    int v = gr / 5600; int k = gr - v*5600;
    float kv = ld(iff, (long)(v*128 + c)*5600 + k, bf);
    xs[kk*XP + c] = f2bu(kv + bs2f(xs[kk*XP + c]));
  }
  __syncthreads();
  if (tid < 256){
    f32x4 acc[4][4];
    #pragma unroll
    for (int mt=0;mt<4;++mt)
      #pragma unroll
      for (int nt=0;nt<4;++nt) acc[mt][nt] = (f32x4){0.f,0.f,0.f,0.f};
    #pragma unroll
    for (int kc = 0; kc < 4; ++kc){
      s16x8 bfr[4];
      #pragma unroll
      for (int nt = 0; nt < 4; ++nt){
        int col = wv*64 + nt*16 + l16;
        bfr[nt] = *(const s16x8*)&wkvT[((size_t)l*256 + col)*128 + kc*32 + quad*8];
      }
      s16x8 afr[4];
      #pragma unroll
      for (int mt = 0; mt < 4; ++mt)
        afr[mt] = *(const s16x8*)&xs[(mt*16 + l16)*XP + kc*32 + quad*8];
      #pragma unroll
      for (int mt = 0; mt < 4; ++mt)
        #pragma unroll
        for (int nt = 0; nt < 4; ++nt)
          acc[mt][nt] = __builtin_amdgcn_mfma_f32_16x16x32_bf16(afr[mt], bfr[nt], acc[mt][nt], 0, 0, 0);
    }
    float bv[4];
    bf16* op[4];
    long ntOff[4];
    #pragma unroll
    for (int nt = 0; nt < 4; ++nt){
      int c = wv*64 + nt*16 + l16;
      bv[nt] = wb[WO_CAQKVB + l*384 + 128 + c];
      int sel = c >> 7, ch = c & 127;
      int h = ch >> 4, d = ch & 15;
      op[nt] = sel ? vh : kh;
      ntOff[nt] = (long)h*89600 + d;
    }
    #pragma unroll
    for (int mt = 0; mt < 4; ++mt)
      #pragma unroll
      for (int i = 0; i < 4; ++i){
        int gr = r0 + mt*16 + quad*4 + i;
        int v = gr / 5600; int k = gr - v*5600;
        long rowOff = (long)v*716800 + (long)k*16;
        #pragma unroll
        for (int nt = 0; nt < 4; ++nt)
          op[nt][rowOff + ntOff[nt]] = f2b(acc[mt][nt][i] + bv[nt]);
      }
  }
}

// ================= self-attn + out-proj + LN1 + ca-q projection =================
__global__ __launch_bounds__(128) void k_self_attn_f(
    const float* __restrict__ qkv, const int* __restrict__ view,
    const float* __restrict__ wb, int l,
    float* __restrict__ q, const float* __restrict__ qpe_g, float* __restrict__ qca){
  __shared__ float att[128];
  __shared__ float red[128];
  __shared__ float xs2[128];
  int n = blockIdx.x, t = threadIdx.x;
  int h = t >> 4, j = t & 15;
  int vn = view[n];
  float qh[16];
  #pragma unroll
  for (int d=0; d<16; ++d) qh[d] = qkv[(size_t)n*384 + h*16 + d] * 0.25f;
  float m = -INFINITY, s = 0.f, o[16];
  #pragma unroll
  for (int d=0; d<16; ++d) o[d]=0.f;
  for (int k = j; k < 200; k += 16){
    float l2;
    if (view[k] != vn){ l2 = -INFINITY; }
    else {
      const float* kr = qkv + (size_t)k*384 + 128 + h*16;
      l2 = 0.f;
      #pragma unroll
      for (int d=0; d<16; ++d) l2 = fmaf(qh[d], kr[d], l2);
    }
    float mn = fmaxf(m, l2);
    float ea = (m > -3.0e38f) ? __expf(m - mn) : 0.f;
    float p  = (l2 > -3.0e38f) ? __expf(l2 - mn) : 0.f;
    s = s*ea + p;
    const float* vr = qkv + (size_t)k*384 + 256 + h*16;
    #pragma unroll
    for (int d=0; d<16; ++d) o[d] = o[d]*ea + p*vr[d];
    m = mn;
  }
  mergeW<16>(m, s, o);
  if (j == 0){
    float inv = (s > 0.f) ? 1.f/s : 0.f;
    #pragma unroll
    for (int d=0; d<16; ++d) att[h*16 + d] = o[d]*inv;
  }
  __syncthreads();
  const float* W = wb + WO_SAOW + l*16384;
  float acc = wb[WO_SAOB + l*128 + t];
  for (int k = 0; k < 128; ++k) acc = fmaf(att[k], W[k*128 + t], acc);
  float v = q[(size_t)n*128 + t] + acc;
  red[t] = v; __syncthreads();
  for (int off=64; off; off>>=1){ if (t<off) red[t]+=red[t+off]; __syncthreads(); }
  float mean = red[0]*(1.f/128.f);
  __syncthreads();
  float d = v - mean;
  red[t] = d*d; __syncthreads();
  for (int off=64; off; off>>=1){ if (t<off) red[t]+=red[t+off]; __syncthreads(); }
  float var = red[0]*(1.f/128.f);
  float r = rsqrtf(var + 1e-5f);
  float qn = d*r*wb[WO_LN1G + l*128 + t] + wb[WO_LN1B + l*128 + t];
  q[(size_t)n*128 + t] = qn;
  xs2[t] = qn + qpe_g[(size_t)n*128 + t];
  __syncthreads();
  const float* Wc = wb + WO_CAQKVW + l*49152;
  float a2 = wb[WO_CAQKVB + l*384 + t];
  for (int k = 0; k < 128; ++k) a2 = fmaf(xs2[k], Wc[k*384 + t], a2);
  qca[(size_t)n*128 + t] = a2;
}

// ================= cross-attention partial (r7 structure, bf16 LDS) =================
__global__ __launch_bounds__(256) void k_cross_part(
    const float* __restrict__ qca, const bf16* __restrict__ kh, const bf16* __restrict__ vh,
    const float* __restrict__ fpos, const float* __restrict__ ctr,
    const float* __restrict__ is2p, const int* __restrict__ qlp,
    float* __restrict__ pm, float* __restrict__ ps, float* __restrict__ po){
  __shared__ __align__(16) unsigned short KV[CK][36];
  __shared__ float2 fp[CK];
  int ch = blockIdx.x, h = blockIdx.y, v = blockIdx.z;
  int t = threadIdx.x;
  int k0 = ch*CK;
  const uint2* ks = (const uint2*)(kh + ((size_t)(v*8 + h)*5600 + k0)*16);
  const uint2* vs = (const uint2*)(vh + ((size_t)(v*8 + h)*5600 + k0)*16);
  for (int i = t; i < CK*4; i += 256){
    int key = i >> 2, part = i & 3;
    *(uint2*)&KV[key][part*4]      = ks[i];
    *(uint2*)&KV[key][16 + part*4] = vs[i];
  }
  if (t < CK) fp[t] = ((const float2*)fpos)[k0 + t];
  __syncthreads();
  int nq = qlp[v];
  const int* ql = qlp + 8 + v*200;
  int g = t >> 5, j = t & 31;
  for (int p = g; p < nq; p += 8){
    int n = ql[p];
    float cx = ctr[2*n], cy = ctr[2*n+1];
    float is2 = is2p[n];
    float qh[16];
    const float* qrow = qca + (size_t)n*128 + h*16;
    #pragma unroll
    for (int d=0; d<16; ++d) qh[d] = qrow[d] * 0.25f;
    float m = -INFINITY, s = 0.f, o[16];
    #pragma unroll
    for (int d=0; d<16; ++d) o[d]=0.f;
    #pragma unroll
    for (int i = 0; i < CK/32; ++i){
      int key = i*32 + j;
      float2 pxy = fp[key];
      float dx = cx - pxy.x, dy = cy - pxy.y;
      float gg = -(dx*dx + dy*dy) * is2;
      const uint2* kp = (const uint2*)&KV[key][0];
      const uint2* vp = (const uint2*)&KV[key][16];
      float kf[16], vf[16];
      #pragma unroll
      for (int u=0; u<4; ++u){
        uint2 a = kp[u]; unpack2(a.x, kf+u*4); unpack2(a.y, kf+u*4+2);
        uint2 b = vp[u]; unpack2(b.x, vf+u*4); unpack2(b.y, vf+u*4+2);
      }
      float l = gg;
      #pragma unroll
      for (int d=0; d<16; ++d) l = fmaf(qh[d], kf[d], l);
      l = (gg < LOG_EPS) ? -INFINITY : l;
      float mn = fmaxf(m, l);
      float ea = (m > -3.0e38f) ? __expf(m - mn) : 0.f;
      float pr = (l > -3.0e38f) ? __expf(l - mn) : 0.f;
      s = s*ea + pr;
      #pragma unroll
      for (int d=0; d<16; ++d) o[d] = o[d]*ea + pr*vf[d];
      m = mn;
    }
    // max-first merge
    float M = m;
    #pragma unroll
    for (int off=16; off>=1; off>>=1) M = fmaxf(M, __shfl_xor(M, off));
    float sc = (m > -3.0e38f) ? __expf(m - M) : 0.f;
    s *= sc;
    #pragma unroll
    for (int d=0; d<16; ++d) o[d] *= sc;
    #pragma unroll
    for (int off=16; off>=1; off>>=1){
      s += __shfl_xor(s, off);
      #pragma unroll
      for (int d=0; d<16; ++d) o[d] += __shfl_xor(o[d], off);
    }
    if (j == 0){
      int idx = (n*NC + ch)*8 + h;
      pm[idx] = M; ps[idx] = s;
      float4* o4 = (float4*)(po + (size_t)idx*16);
      o4[0] = make_float4(o[0],o[1],o[2],o[3]);
      o4[1] = make_float4(o[4],o[5],o[6],o[7]);
      o4[2] = make_float4(o[8],o[9],o[10],o[11]);
      o4[3] = make_float4(o[12],o[13],o[14],o[15]);
    }
  }
}

// ================= tail =================
__global__ __launch_bounds__(256) void k_tail(
    const float* __restrict__ pm, const float* __restrict__ ps, const float* __restrict__ po,
    const float* __restrict__ wb, int l, float* __restrict__ q,
    const void* __restrict__ niqp, void* __restrict__ out, long outOff,
    float* __restrict__ is2p, int last, const void* __restrict__ ln1g){
  __shared__ float att[128];
  __shared__ float sm[2][128], ss[2][128], so[2][128];
  __shared__ float part[256];
  __shared__ float redw[4];
  __shared__ float xs[128];
  __shared__ float hs[256];
  __shared__ float ac6[6*128];
  __shared__ float bbv[8];
  int bf = get_bf(ln1g);
  int n = blockIdx.x, t = threadIdx.x;
  int tc = t & 127, half = t >> 7;
  {
    int h = tc >> 4, d = tc & 15;
    int c0 = half ? 18 : 0, c1 = half ? NC : 18;
    float m = -INFINITY, s = 0.f, o = 0.f;
    for (int c = c0; c < c1; ++c){
      int idx = (n*NC + c)*8 + h;
      float mc = pm[idx], sc = ps[idx], oc = po[(size_t)idx*16 + d];
      float mn = fmaxf(m, mc);
      float ea = (m  > -3.0e38f) ? __expf(m  - mn) : 0.f;
      float eb = (mc > -3.0e38f) ? __expf(mc - mn) : 0.f;
      s = s*ea + sc*eb;
      o = o*ea + oc*eb;
      m = mn;
    }
    sm[half][tc]=m; ss[half][tc]=s; so[half][tc]=o;
  }
  __syncthreads();
  if (t < 128){
    float m1=sm[0][t], m2=sm[1][t];
    float mn=fmaxf(m1,m2);
    float e1=(m1>-3.0e38f)?__expf(m1-mn):0.f, e2=(m2>-3.0e38f)?__expf(m2-mn):0.f;
    float s = ss[0][t]*e1 + ss[1][t]*e2;
    float o = so[0][t]*e1 + so[1][t]*e2;
    att[t] = (s>0.f)? o/s : 0.f;
  }
  __syncthreads();
  {
    const float* W = wb + WO_CAOW + l*16384;
    float a = 0.f;
    for (int k = half*64; k < half*64+64; ++k) a = fmaf(att[k], W[k*128 + tc], a);
    part[t] = a;
  }
  __syncthreads();
  float v = (t<128) ? q[(size_t)n*128 + t] + part[t] + part[128+t] + wb[WO_CAOB + l*128 + t] : 0.f;
  float sv = wsum64(v);
  if ((t&63)==0) redw[t>>6] = sv;
  __syncthreads();
  float mean = (redw[0]+redw[1]+redw[2]+redw[3]) * (1.f/128.f);
  __syncthreads();
  float d = (t<128)? v-mean : 0.f;
  sv = wsum64(d*d);
  if ((t&63)==0) redw[t>>6] = sv;
  __syncthreads();
  float var = (redw[0]+redw[1]+redw[2]+redw[3]) * (1.f/128.f);
  float r = rsqrtf(var + 1e-5f);
  if (t<128) xs[t] = d*r*wb[WO_LN2G + l*128 + t] + wb[WO_LN2B + l*128 + t];
  __syncthreads();
  {
    const float* W = wb + WO_FW1 + l*32768;
    float a = wb[WO_FB1 + l*256 + t];
    for (int k=0;k<128;++k) a = fmaf(xs[k], W[k*256 + t], a);
    hs[t] = fmaxf(a, 0.f);
  }
  __syncthreads();
  {
    const float* W = wb + WO_FW2 + l*32768;
    float a = 0.f;
    for (int k=half*128;k<half*128+128;++k) a = fmaf(hs[k], W[k*128 + tc], a);
    part[t] = a;
  }
  __syncthreads();
  v = (t<128) ? xs[t] + part[t] + part[128+t] + wb[WO_FB2 + l*128 + t] : 0.f;
  sv = wsum64(v);
  if ((t&63)==0) redw[t>>6] = sv;
  __syncthreads();
  mean = (redw[0]+redw[1]+redw[2]+redw[3]) * (1.f/128.f);
  __syncthreads();
  d = (t<128)? v-mean : 0.f;
  sv = wsum64(d*d);
  if ((t&63)==0) redw[t>>6] = sv;
  __syncthreads();
  var = (redw[0]+redw[1]+redw[2]+redw[3]) * (1.f/128.f);
  r = rsqrtf(var + 1e-5f);
  if (t<128){
    float q3 = d*r*wb[WO_LN3G + l*128 + t] + wb[WO_LN3B + l*128 + t];
    q[(size_t)n*128 + t] = q3;
    xs[t] = q3;
    if (last) st(out, (long)t*200 + n, q3, bf);
  }
  __syncthreads();
  {
    const float* W = wb + WO_PW1;
    float a = 0.f;
    for (int k=half*64;k<half*64+64;++k) a = fmaf(xs[k], W[k*128 + tc], a);
    part[t] = a;
  }
  __syncthreads();
  if (t<128){
    float x = fmaxf(part[t] + part[128+t] + wb[WO_PB1 + t], 0.f);
    #pragma unroll
    for (int c=0;c<6;++c) ac6[c*128+t] = x * wb[WO_PW2 + t*6 + c];
  }
  __syncthreads();
  for (int off=64; off; off>>=1){
    if (t < off){
      #pragma unroll
      for (int c=0;c<6;++c) ac6[c*128+t] += ac6[c*128+t+off];
    }
    __syncthreads();
  }
  if (t < 6){
    float raw = ac6[t*128] + wb[WO_PB2 + t];
    if (t < 2) raw += ld(niqp, 2*n + t, bf);
    float svv = sigm(raw);
    st(out, outOff + n*6 + t, svv, bf);
    bbv[t] = svv;
  }
  __syncthreads();
  if (t == 0){
    float dxv = sigm(bbv[2]) * IMGX;
    float dyv = sigm(bbv[3]) * IMGY;
    float rad = ceilf(sqrtf(dxv*dxv + dyv*dyv) * 0.5f);
    float sg = (rad*2.f + 1.f) * (1.f/6.f);
    is2p[n] = 1.f/(2.f*sg*sg);
  }
}

// ================= launch =================
extern "C" void kernel_launch(void* const* d_in, const int* in_sizes, int n_in,
                              void* d_out, int out_size, void* d_ws, size_t ws_size,
                              hipStream_t stream){
  const void* iqf   = d_in[0];
  const void* niqp  = d_in[1];
  const void* iff   = d_in[2];
  const void* nifp  = d_in[3];
  const void* l2i   = d_in[4];
  const int*  view  = (const int*)d_in[5];
  const void* ln1_g = d_in[14];

  float* fw = (float*)d_ws;
  float* q    = fw + OFF_Q;
  float* qpe  = fw + OFF_QPE;
  float* qca  = fw + OFF_QCA;
  float* tmp  = fw + OFF_TMP;
  float* pm   = fw + OFF_PM;
  float* ps   = fw + OFF_PS;
  float* po   = fw + OFF_PO;
  float* fpos = fw + OFF_FPOS;
  float* ctr  = fw + OFF_CTR;
  float* sig2 = fw + OFF_SIG;
  int*   qlp  = (int*)(fw + OFF_QL);
  float* wb   = fw + OFF_WB;
  bf16* bw   = (bf16*)((char*)d_ws + F_TOTAL*sizeof(float));
  bf16* kh   = bw + B_KH;
  bf16* vh   = bw + B_VH;
  bf16* wkvT = bw + B_WKVT;
  bf16* kw2T = bw + B_KW2T;

  CvtArgs ca;
  ca.s[0]  = {d_in[6],  WO_SAQKVW, 98304};
  ca.s[1]  = {d_in[7],  WO_SAQKVB, 768};
  ca.s[2]  = {d_in[8],  WO_SAOW,   32768};
  ca.s[3]  = {d_in[9],  WO_SAOB,   256};
  ca.s[4]  = {d_in[10], WO_CAQKVW, 98304};
  ca.s[5]  = {d_in[11], WO_CAQKVB, 768};
  ca.s[6]  = {d_in[12], WO_CAOW,   32768};
  ca.s[7]  = {d_in[13], WO_CAOB,   256};
  ca.s[8]  = {d_in[14], WO_LN1G,   256};
  ca.s[9]  = {d_in[15], WO_LN1B,   256};
  ca.s[10] = {d_in[16], WO_LN2G,   256};
  ca.s[11] = {d_in[17], WO_LN2B,   256};
  ca.s[12] = {d_in[18], WO_LN3G,   256};
  ca.s[13] = {d_in[19], WO_LN3B,   256};
  ca.s[14] = {d_in[20], WO_FW1,    65536};
  ca.s[15] = {d_in[21], WO_FB1,    512};
  ca.s[16] = {d_in[22], WO_FW2,    65536};
  ca.s[17] = {d_in[23], WO_FB2,    256};
  ca.s[18] = {d_in[24], WO_QW1,    512};
  ca.s[19] = {d_in[25], WO_QB1,    256};
  ca.s[20] = {d_in[26], WO_QW2,    32768};
  ca.s[21] = {d_in[27], WO_QB2,    256};
  ca.s[22] = {d_in[28], WO_KW1,    512};
  ca.s[23] = {d_in[29], WO_KB1,    256};
  ca.s[24] = {d_in[31], WO_KB2,    256};
  ca.s[25] = {d_in[32], WO_PW1,    16384};
  ca.s[26] = {d_in[33], WO_PB1,    128};
  ca.s[27] = {d_in[34], WO_PW2,    768};
  ca.s[28] = {d_in[35], WO_PB2,    6};

  k_cvt<<<dim3(30,8), 256, 0, stream>>>(ca, wb, qlp, view, ln1_g);
  k_wT<<<dim3(384,2), 128, 0, stream>>>(d_in[10], d_in[30], wkvT, kw2T, ln1_g);
  k_prep2<<<200, 128, 0, stream>>>(niqp, l2i, nifp, view, iqf, ctr, fpos, q, wb, sig2, d_out, ln1_g);

  for (int l = 0; l < 2; ++l){
    k_kvq<<<725, 384, 0, stream>>>(nifp, iff, niqp, q, wb, l, kw2T, wkvT, kh, vh, qpe, tmp, ln1_g);
    k_self_attn_f<<<200, 128, 0, stream>>>(tmp, view, wb, l, q, qpe, qca);
    k_cross_part<<<dim3(NC,8,6), 256, 0, stream>>>(qca, kh, vh, fpos, ctr, sig2, qlp, pm, ps, po);
    k_tail<<<200, 256, 0, stream>>>(pm, ps, po, wb, l, q, niqp, d_out,
                                    (l==0 ? 45200L : 46400L), sig2, (l==1) ? 1 : 0, ln1_g);
  }
}